// Round 19
// baseline (2942.882 us; speedup 1.0000x reference)
//
#include <hip/hip_runtime.h>
#include <hip/hip_bf16.h>
#include <math.h>

#define B_   16
#define S_   1024
#define R_   512
#define H_   512
#define HD_  256
#define G_   1024
#define DIN_ 1536

// ---------------------------------------------------------------------------
// bf16 helpers
// ---------------------------------------------------------------------------
__device__ inline unsigned short bf16_rtn(float x)
{
    unsigned u = __float_as_uint(x);
    u += 0x7FFFu + ((u >> 16) & 1);
    return (unsigned short)(u >> 16);
}

__device__ inline unsigned pk_bf16(float lo, float hi)
{
    return (unsigned)bf16_rtn(lo) | ((unsigned)bf16_rtn(hi) << 16);
}

// generic fp32 -> bf16 pack, 4 elems/thread
__global__ __launch_bounds__(256) void pack_bf16(const float* __restrict__ src,
                                                 unsigned short* __restrict__ dst,
                                                 long n4)
{
    const long i = (long)blockIdx.x * 256 + threadIdx.x;
    if (i >= n4) return;
    const float4 v = *((const float4*)src + i);
    uint2 u;
    u.x = pk_bf16(v.x, v.y);
    u.y = pk_bf16(v.z, v.w);
    *((uint2*)dst + i) = u;
}

// fp32 -> (bf16 hi, bf16 lo) split pack: x ~= hi + lo with rel err ~2^-17
__global__ __launch_bounds__(256) void pack_hilo(const float* __restrict__ src,
                                                 unsigned short* __restrict__ hi,
                                                 unsigned short* __restrict__ lo,
                                                 long n4)
{
    const long i = (long)blockIdx.x * 256 + threadIdx.x;
    if (i >= n4) return;
    const float4 v = *((const float4*)src + i);
    float vv[4] = {v.x, v.y, v.z, v.w};
    unsigned short h[4], L[4];
#pragma unroll
    for (int e = 0; e < 4; ++e) {
        h[e] = bf16_rtn(vv[e]);
        const float hf = __uint_as_float((unsigned)h[e] << 16);
        L[e] = bf16_rtn(vv[e] - hf);
    }
    uint2 uh, ul;
    uh.x = (unsigned)h[0] | ((unsigned)h[1] << 16);
    uh.y = (unsigned)h[2] | ((unsigned)h[3] << 16);
    ul.x = (unsigned)L[0] | ((unsigned)L[1] << 16);
    ul.y = (unsigned)L[2] | ((unsigned)L[3] << 16);
    *((uint2*)hi + i) = uh;
    *((uint2*)lo + i) = ul;
}

typedef __attribute__((ext_vector_type(4))) float f32x4;
typedef __attribute__((ext_vector_type(8))) short bf16x8;

__device__ inline bf16x8 u4_to_b8(uint4 u)
{
    bf16x8 r;
    __builtin_memcpy(&r, &u, 16);
    return r;
}

// ---------------------------------------------------------------------------
// Split-bf16 MFMA GEMM (fp32-class accuracy): C = A.B^T (+bias, opt tanh)
// A ~= Ahi+Alo, B ~= Bhi+Blo; acc += AhiBhi + AloBhi + AhiBlo (err ~2^-17).
// Strided batched: row m of A at Ahi + bb*a_bs + m*lda (k-contiguous).
// Used for steps 1,2 whose outputs feed softmax (bf16-only was absmax-risky).
// Fragment mapping per guide §3 (m89-verified, same as all MFMA kernels here).
// ---------------------------------------------------------------------------
__global__ __launch_bounds__(256) void gemm_split(
    const unsigned short* __restrict__ Ahi, const unsigned short* __restrict__ Alo,
    long a_bs, long lda,
    const unsigned short* __restrict__ Bhi, const unsigned short* __restrict__ Blo,
    long b_bs, long ldb,
    float* __restrict__ C, long c_bs, int ldc,
    const float* __restrict__ bias, int do_tanh, int K)
{
    const int bb = blockIdx.z;
    const int n0 = blockIdx.x * 64, m0 = blockIdx.y * 64;
    const int lane = threadIdx.x & 63, w = threadIdx.x >> 6;
    const int lr = lane & 15, lk = lane >> 4;
    const long boff = bb * b_bs + (long)(n0 + 16 * w + lr) * ldb + lk * 8;
    const unsigned short* bh = Bhi + boff;
    const unsigned short* bl = Blo + boff;

    f32x4 acc[4];
#pragma unroll
    for (int mi = 0; mi < 4; ++mi) acc[mi] = (f32x4){0.f, 0.f, 0.f, 0.f};

    for (int k0 = 0; k0 < K; k0 += 32) {
        const bf16x8 bhf = *(const bf16x8*)(bh + k0);
        const bf16x8 blf = *(const bf16x8*)(bl + k0);
#pragma unroll
        for (int mi = 0; mi < 4; ++mi) {
            const long aoff = bb * a_bs + (long)(m0 + 16 * mi + lr) * lda + lk * 8 + k0;
            const bf16x8 ahf = *(const bf16x8*)(Ahi + aoff);
            const bf16x8 alf = *(const bf16x8*)(Alo + aoff);
            acc[mi] = __builtin_amdgcn_mfma_f32_16x16x32_bf16(ahf, bhf, acc[mi], 0, 0, 0);
            acc[mi] = __builtin_amdgcn_mfma_f32_16x16x32_bf16(alf, bhf, acc[mi], 0, 0, 0);
            acc[mi] = __builtin_amdgcn_mfma_f32_16x16x32_bf16(ahf, blf, acc[mi], 0, 0, 0);
        }
    }
    const int n = n0 + 16 * w + lr;
    const float bv = bias ? bias[n] : 0.f;
#pragma unroll
    for (int mi = 0; mi < 4; ++mi)
#pragma unroll
        for (int r = 0; r < 4; ++r) {
            float v = acc[mi][r] + bv;
            if (do_tanh) v = tanhf(v);
            C[bb * c_bs + (long)(m0 + 16 * mi + lk * 4 + r) * ldc + n] = v;
        }
}

// ---------------------------------------------------------------------------
// Softmax over r (last axis, contiguous, 512): one wave per row, in-place
// ---------------------------------------------------------------------------
__global__ __launch_bounds__(256) void softmax_rows(float* __restrict__ l)
{
    const int lane = threadIdx.x & 63;
    const int wv = threadIdx.x >> 6;
    const long row = (long)blockIdx.x * 4 + wv;
    float* p = l + row * R_;
    float4 v0 = ((const float4*)p)[lane * 2];
    float4 v1 = ((const float4*)p)[lane * 2 + 1];
    float m = fmaxf(fmaxf(fmaxf(v0.x, v0.y), fmaxf(v0.z, v0.w)),
                    fmaxf(fmaxf(v1.x, v1.y), fmaxf(v1.z, v1.w)));
#pragma unroll
    for (int o = 32; o; o >>= 1) m = fmaxf(m, __shfl_xor(m, o));
    v0.x = __expf(v0.x - m); v0.y = __expf(v0.y - m);
    v0.z = __expf(v0.z - m); v0.w = __expf(v0.w - m);
    v1.x = __expf(v1.x - m); v1.y = __expf(v1.y - m);
    v1.z = __expf(v1.z - m); v1.w = __expf(v1.w - m);
    float s = v0.x + v0.y + v0.z + v0.w + v1.x + v1.y + v1.z + v1.w;
#pragma unroll
    for (int o = 32; o; o >>= 1) s += __shfl_xor(s, o);
    const float inv = 1.f / s;
    v0.x *= inv; v0.y *= inv; v0.z *= inv; v0.w *= inv;
    v1.x *= inv; v1.y *= inv; v1.z *= inv; v1.w *= inv;
    ((float4*)p)[lane * 2] = v0;
    ((float4*)p)[lane * 2 + 1] = v1;
}

// ---------------------------------------------------------------------------
// Softmax over s (axis 1, stride R) -> bf16 output
// ---------------------------------------------------------------------------
__global__ __launch_bounds__(512) void softmax_cols(const float* __restrict__ l,
                                                    unsigned short* __restrict__ asb)
{
    const int b = blockIdx.y;
    const int rl = threadIdx.x & 127;
    const int r = blockIdx.x * 128 + rl;
    const int sg = threadIdx.x >> 7;           // 0..3
    const int s0 = sg * (S_ / 4), s1 = s0 + S_ / 4;
    const float* base = l + (long)b * S_ * R_ + r;
    __shared__ float red[4][128];

    float pm = -1e30f;
    for (int s = s0; s < s1; ++s) pm = fmaxf(pm, base[(long)s * R_]);
    red[sg][rl] = pm;
    __syncthreads();
    const float m = fmaxf(fmaxf(red[0][rl], red[1][rl]), fmaxf(red[2][rl], red[3][rl]));
    __syncthreads();

    float ps = 0.f;
    for (int s = s0; s < s1; ++s) ps += __expf(base[(long)s * R_] - m);
    red[sg][rl] = ps;
    __syncthreads();
    const float inv = 1.f / (red[0][rl] + red[1][rl] + red[2][rl] + red[3][rl]);

    unsigned short* ob = asb + (long)b * S_ * R_ + r;
    for (int s = s0; s < s1; ++s)
        ob[(long)s * R_] = bf16_rtn(__expf(base[(long)s * R_] - m) * inv);
}

// ---------------------------------------------------------------------------
// cat_bf rows 0..511: cat_bf[b][h][s] = bf16(h_s[b][s][h])
// ---------------------------------------------------------------------------
__global__ __launch_bounds__(256) void transpose_hs(const float* __restrict__ hs,
                                                    unsigned short* __restrict__ catb)
{
    __shared__ float tile[32][33];
    const int b = blockIdx.z;
    const int s0 = blockIdx.x * 32, h0 = blockIdx.y * 32;
    const int tx = threadIdx.x, ty = threadIdx.y;
#pragma unroll
    for (int i = 0; i < 32; i += 8)
        tile[ty + i][tx] = hs[((long)b * S_ + s0 + ty + i) * H_ + h0 + tx];
    __syncthreads();
#pragma unroll
    for (int i = 0; i < 32; i += 8)
        catb[((long)b * 2 * H_ + h0 + ty + i) * S_ + s0 + tx] = bf16_rtn(tile[tx][ty + i]);
}

// ---------------------------------------------------------------------------
// refT_bf[b][h][r] = bf16(ref[r][b][h])
// ---------------------------------------------------------------------------
__global__ __launch_bounds__(256) void transpose_ref(const float* __restrict__ ref,
                                                     unsigned short* __restrict__ refT)
{
    __shared__ float tile[32][33];
    const int b = blockIdx.z;
    const int r0 = blockIdx.x * 32, h0 = blockIdx.y * 32;
    const int tx = threadIdx.x, ty = threadIdx.y;
#pragma unroll
    for (int i = 0; i < 32; i += 8)
        tile[ty + i][tx] = ref[((long)(r0 + ty + i) * B_ + b) * H_ + h0 + tx];
    __syncthreads();
#pragma unroll
    for (int i = 0; i < 32; i += 8)
        refT[((long)b * H_ + h0 + ty + i) * R_ + r0 + tx] = bf16_rtn(tile[tx][ty + i]);
}

// ---------------------------------------------------------------------------
// a_rT_bf[b][r][s] = bf16(l[b][s][r])   (l holds a_r after softmax_rows)
// ---------------------------------------------------------------------------
__global__ __launch_bounds__(256) void transpose_arT(const float* __restrict__ l,
                                                     unsigned short* __restrict__ arT)
{
    __shared__ float tile[32][33];
    const int b = blockIdx.z;
    const int s0 = blockIdx.x * 32, r0 = blockIdx.y * 32;
    const int tx = threadIdx.x, ty = threadIdx.y;
#pragma unroll
    for (int i = 0; i < 32; i += 8)
        tile[ty + i][tx] = l[((long)b * S_ + s0 + ty + i) * R_ + r0 + tx];
    __syncthreads();
#pragma unroll
    for (int i = 0; i < 32; i += 8)
        arT[((long)b * R_ + r0 + ty + i) * S_ + s0 + tx] = bf16_rtn(tile[tx][ty + i]);
}

// ---------------------------------------------------------------------------
// bin_bf16[t*B+b][0:1024] = bf16(c_r[b][t][:]); [1024:1536] = bf16(ref[t][b][:])
// ---------------------------------------------------------------------------
__global__ __launch_bounds__(256) void build_bin(const float* __restrict__ cr,
                                                 const float* __restrict__ ref,
                                                 unsigned short* __restrict__ binb)
{
    const long idx4 = (long)blockIdx.x * blockDim.x + threadIdx.x;
    if (idx4 >= (long)R_ * B_ * DIN_ / 4) return;
    const long f = idx4 * 4;
    const int d = (int)(f % DIN_);
    const long tb = f / DIN_;
    const int b = (int)(tb % B_);
    const int t = (int)(tb / B_);
    float4 v;
    if (d < 2 * H_) v = *(const float4*)(cr + ((long)b * R_ + t) * (2 * H_) + d);
    else            v = *(const float4*)(ref + ((long)t * B_ + b) * H_ + (d - 2 * H_));
    uint2 u;
    u.x = pk_bf16(v.x, v.y);
    u.y = pk_bf16(v.z, v.w);
    *((uint2*)binb + idx4) = u;
}

// ---------------------------------------------------------------------------
// One-time W_hh transpose + bf16 pack: WB[dir][q2][g] (q2 = 4*kk + kgroup)
// ---------------------------------------------------------------------------
__global__ __launch_bounds__(256) void transpose_w_bf16(
    const float* __restrict__ Whh_f, const float* __restrict__ Whh_b,
    unsigned* __restrict__ WB)
{
    const int g = blockIdx.x * 256 + threadIdx.x;   // 0..1023
    const int q2 = blockIdx.y;                      // 0..31
    const int dir = blockIdx.z;
    const float* W = dir ? Whh_b : Whh_f;
    const float4 a = *(const float4*)(W + (long)g * HD_ + q2 * 8);
    const float4 b = *(const float4*)(W + (long)g * HD_ + q2 * 8 + 4);
    uint4 u;
    u.x = pk_bf16(a.x, a.y);
    u.y = pk_bf16(a.z, a.w);
    u.z = pk_bf16(b.x, b.y);
    u.w = pk_bf16(b.z, b.w);
    *((uint4*)WB + ((long)dir * 32 + q2) * 1024 + g) = u;
}

// ---------------------------------------------------------------------------
// Generic bf16 MFMA GEMM, 64x64 tile, batched, both operands k-contiguous.
// CT=0: bf16 row-major C[m][n]. CT=1: fp32 TRANSPOSED write C[n][m] (float4).
// ---------------------------------------------------------------------------
template<int CT>
__global__ __launch_bounds__(256) void gemm56(
    const unsigned short* __restrict__ A, long a_bs, int lda,
    const unsigned short* __restrict__ Bm, long b_bs, int ldb,
    void* __restrict__ Cv, long c_bs, int ldc, int K)
{
    const int bb = blockIdx.z;
    const int n0 = blockIdx.x * 64, m0 = blockIdx.y * 64;
    const int lane = threadIdx.x & 63, w = threadIdx.x >> 6;
    const int lr = lane & 15, lk = lane >> 4;
    const unsigned short* ap = A + bb * a_bs + (long)(m0 + lr) * lda + lk * 8;
    const unsigned short* bp = Bm + bb * b_bs + (long)(n0 + 16 * w + lr) * ldb + lk * 8;

    f32x4 acc[4];
#pragma unroll
    for (int mi = 0; mi < 4; ++mi) acc[mi] = (f32x4){0.f, 0.f, 0.f, 0.f};

    for (int k0 = 0; k0 < K; k0 += 32) {
        const bf16x8 bfr = *(const bf16x8*)(bp + k0);
#pragma unroll
        for (int mi = 0; mi < 4; ++mi) {
            const bf16x8 afr = *(const bf16x8*)(ap + (long)mi * 16 * lda + k0);
            acc[mi] = __builtin_amdgcn_mfma_f32_16x16x32_bf16(afr, bfr, acc[mi], 0, 0, 0);
        }
    }
    const int n = n0 + 16 * w + lr;
    if (CT == 0) {
        unsigned short* C = (unsigned short*)Cv + bb * c_bs;
#pragma unroll
        for (int mi = 0; mi < 4; ++mi)
#pragma unroll
            for (int r = 0; r < 4; ++r)
                C[(long)(m0 + 16 * mi + lk * 4 + r) * ldc + n] = bf16_rtn(acc[mi][r]);
    } else {
        float* C = (float*)Cv + bb * c_bs;
#pragma unroll
        for (int mi = 0; mi < 4; ++mi) {
            float4 v = make_float4(acc[mi][0], acc[mi][1], acc[mi][2], acc[mi][3]);
            *(float4*)&C[(long)n * ldc + m0 + 16 * mi + lk * 4] = v;
        }
    }
}

// ---------------------------------------------------------------------------
// Step-8 GEMM via MFMA: xg[m][n] = sum_k bin_bf[m][k]*Wih_bf[n][k] + bias(n)
// ---------------------------------------------------------------------------
__global__ __launch_bounds__(256) void gemm_xg_mfma(
    const unsigned short* __restrict__ binb, const unsigned short* __restrict__ Wb,
    const float* __restrict__ bihf, const float* __restrict__ bhhf,
    const float* __restrict__ bihb, const float* __restrict__ bhhb,
    float* __restrict__ xgf2, float* __restrict__ xgb2)
{
    const int dir = blockIdx.z;
    const int n0 = blockIdx.x * 64;
    const int m0 = blockIdx.y * 64;
    const int lane = threadIdx.x & 63, w = threadIdx.x >> 6;
    const int lr = lane & 15, lk = lane >> 4;
    const unsigned short* Wd = Wb + (long)dir * G_ * DIN_;
    const float* bi = dir ? bihb : bihf;
    const float* bh = dir ? bhhb : bhhf;
    float* xg = dir ? xgb2 : xgf2;

    const int n = n0 + 16 * w + lr;
    const unsigned short* bp = Wd + (long)n * DIN_ + lk * 8;
    const unsigned short* ap = binb + (long)(m0 + lr) * DIN_ + lk * 8;

    f32x4 acc[4];
#pragma unroll
    for (int mi = 0; mi < 4; ++mi) acc[mi] = (f32x4){0.f, 0.f, 0.f, 0.f};

    for (int k0 = 0; k0 < DIN_; k0 += 32) {
        const bf16x8 bfr = *(const bf16x8*)(bp + k0);
#pragma unroll
        for (int mi = 0; mi < 4; ++mi) {
            const bf16x8 afr = *(const bf16x8*)(ap + (long)mi * 16 * DIN_ + k0);
            acc[mi] = __builtin_amdgcn_mfma_f32_16x16x32_bf16(afr, bfr, acc[mi], 0, 0, 0);
        }
    }
    const float bias = bi[n] + bh[n];
#pragma unroll
    for (int mi = 0; mi < 4; ++mi)
#pragma unroll
        for (int r = 0; r < 4; ++r) {
            const int m = m0 + 16 * mi + lk * 4 + r;
            xg[(long)m * G_ + n] = acc[mi][r] + bias;
        }
}

// ---------------------------------------------------------------------------
// Bi-LSTM scan v11 — W fully LDS-resident, 4 blocks/dir (R18-proven), plus:
//  (a) DEFERRED out write: the HBM out store now issues AFTER the flag store,
//      removing an HBM drain (~0.3-0.5us) from the per-step sync critical
//      path (the cell-phase __syncthreads' vmcnt(0) no longer waits on it)
//  (b) double-buffered h_lds; own 64-col slice written straight to LDS in
//      the cell phase; stage phase fetches only the other 3 blocks' 6 KB
// Sync protocol unchanged (R7/R18-proven flag+fence).
// ---------------------------------------------------------------------------
#define NBD 4

__device__ inline float sig_(float x) { return 1.f / (1.f + __expf(-x)); }

__global__ __launch_bounds__(256) void lstm_scan_s(
    const float* __restrict__ xg_f, const float* __restrict__ xg_b,
    const uint4* __restrict__ WBu, unsigned short* __restrict__ hbuf,
    unsigned* __restrict__ flags, float* __restrict__ out)
{
    const int blk = blockIdx.x;
    const int dir = blk >> 2;
    const int j = blk & 3;
    const float* xg = dir ? xg_b : xg_f;
    const uint4* Wg = WBu + (long)dir * 32768;        // [q2 0..31][g 0..1023]
    unsigned short* hb = hbuf + dir * (2 * B_ * HD_); // 2 parity x [16][256]
    unsigned* fl = flags + dir * 64;

    __shared__ uint4 WL[32 * 256];                    // 128 KB (full W slice)
    __shared__ unsigned short h_lds[2][16 * 264];     // 16.5 KB dbuf staged h

    const int tid = threadIdx.x;
    const int lane = tid & 63, w = tid >> 6;          // 4 waves
    const int lcol = lane & 15, lkg = lane >> 4;

    // fill WL once: local row = g*64 + c  <-  global gate row g*256 + 64j + c
    for (int idx = tid; idx < 32 * 256; idx += 256) {
        const int q2 = idx >> 8, loc = idx & 255;
        const int g = loc >> 6, c = loc & 63;
        WL[idx] = Wg[q2 * 1024 + g * 256 + 64 * j + c];
    }
    for (int i = tid; i < 16 * 264; i += 256) h_lds[0][i] = 0;
    float c_reg[4] = {};
    const int col = 64 * j + 16 * w + lcol;           // owned h-column
    __syncthreads();

    for (int t = 0; t < R_; ++t) {
        const int tt = dir ? (R_ - 1 - t) : t;
        const int p = t & 1;

        // prefetch xg (immutable; latency hides under the flag poll)
        float xgv[4][4];
#pragma unroll
        for (int g = 0; g < 4; ++g)
#pragma unroll
            for (int r = 0; r < 4; ++r)
                xgv[g][r] = xg[((long)tt * B_ + lkg * 4 + r) * G_ + g * 256 + col];

        if (t > 0) {
            if (tid < 64) {
                while (true) {
                    unsigned v = (lane < NBD)
                        ? __hip_atomic_load(&fl[lane * 16], __ATOMIC_RELAXED,
                                            __HIP_MEMORY_SCOPE_AGENT)
                        : 0xFFFFFFFFu;
                    if (__all(v >= (unsigned)t)) break;
                    __builtin_amdgcn_s_sleep(1);
                }
            }
            __syncthreads();
            __builtin_amdgcn_fence(__ATOMIC_ACQUIRE, "agent");

            // stage ONLY the other 3 blocks' 64-col slices (384 uint4)
            for (int i = tid; i < 384; i += 256) {
                const int si = i >> 7;                 // 0..2
                const int jo = si + (si >= j);
                const int rr = i & 127;
                const int b = rr >> 3, c8 = 64 * jo + (rr & 7) * 8;
                *(uint4*)&h_lds[p][b * 264 + c8] =
                    *(const uint4*)&hb[p * (B_ * HD_) + b * HD_ + c8];
            }
            __syncthreads();
        }

        // dot: wave w's 4 gate tiles, all LDS-fed
        f32x4 acc[4];
#pragma unroll
        for (int g = 0; g < 4; ++g) acc[g] = (f32x4){0.f, 0.f, 0.f, 0.f};
        const unsigned short* hrow = &h_lds[p][lcol * 264 + lkg * 8];
#pragma unroll
        for (int kk = 0; kk < 8; ++kk) {
            const bf16x8 a_ = *(const bf16x8*)(hrow + 32 * kk);
#pragma unroll
            for (int g = 0; g < 4; ++g) {
                const uint4 wv = WL[(4 * kk + lkg) * 256 + g * 64 + 16 * w + lcol];
                acc[g] = __builtin_amdgcn_mfma_f32_16x16x32_bf16(
                    a_, u4_to_b8(wv), acc[g], 0, 0, 0);
            }
        }

        // cell: lane owns (batch = lkg*4+r, col); write hb + own LDS slice
        float hsv[4];
#pragma unroll
        for (int r = 0; r < 4; ++r) {
            const int batch = lkg * 4 + r;
            const float iv = acc[0][r] + xgv[0][r];
            const float fv = acc[1][r] + xgv[1][r];
            const float gv = acc[2][r] + xgv[2][r];
            const float ov = acc[3][r] + xgv[3][r];
            float ax = fabsf(gv);
            float tg = copysignf(1.f - 2.f / (1.f + __expf(2.f * ax)), gv);
            float c = sig_(fv) * c_reg[r] + sig_(iv) * tg;
            c_reg[r] = c;
            float ac = fabsf(c);
            float tc = copysignf(1.f - 2.f / (1.f + __expf(2.f * ac)), c);
            const float h = sig_(ov) * tc;
            hsv[r] = h;
            const unsigned short hb16 = bf16_rtn(h);
            hb[(p ^ 1) * (B_ * HD_) + batch * HD_ + col] = hb16;
            h_lds[p ^ 1][batch * 264 + col] = hb16;
        }
        __syncthreads();   // drains hb stores (vmcnt(0)); orders LDS writes
        if (tid == 0) {
            __threadfence();   // wbl2: h lines -> LLC (R7-proven)
            __hip_atomic_store(&fl[j * 16], (unsigned)(t + 1), __ATOMIC_RELAXED,
                               __HIP_MEMORY_SCOPE_AGENT);
        }
        // DEFERRED out writes: off the flag critical path
#pragma unroll
        for (int r = 0; r < 4; ++r)
            out[((long)tt * B_ + lkg * 4 + r) * (2 * HD_) + dir * HD_ + col] = hsv[r];
    }
}

// ---------------------------------------------------------------------------
extern "C" void kernel_launch(void* const* d_in, const int* in_sizes, int n_in,
                              void* d_out, int out_size, void* d_ws, size_t ws_size,
                              hipStream_t stream)
{
    const float* src  = (const float*)d_in[1];   // [S][B][H]
    const float* ref  = (const float*)d_in[2];   // [R][B][H]
    const float* Wref = (const float*)d_in[3];   // [H][H]
    const float* bref = (const float*)d_in[4];   // [H]
    const float* Wihf = (const float*)d_in[5];   // [G][DIN]
    const float* Whhf = (const float*)d_in[6];   // [G][HD]
    const float* bihf = (const float*)d_in[7];
    const float* bhhf = (const float*)d_in[8];
    const float* Wihb = (const float*)d_in[9];
    const float* Whhb = (const float*)d_in[10];
    const float* bihb = (const float*)d_in[11];
    const float* bhhb = (const float*)d_in[12];
    float* out = (float*)d_out;                  // [R][B][2*HD]

    float* ws = (float*)d_ws;
    // workspace layout (float offsets); hi/lo split buffers alias regions
    // that are dead during steps 0-2:
    float* hs   = ws + 0L;                              // [B][S][H] fp32
    float* l    = ws + 8388608L;                        // [B][S][R] fp32
    unsigned short* as_bf = (unsigned short*)(ws + 16777216L);  // bf16 [B][S][R]
    unsigned short* refT  = (unsigned short*)(ws + 20971520L);  // bf16 [B][H][R]
    unsigned short* a_rT  = (unsigned short*)(ws + 23068672L);  // bf16 [B][R][S]
    unsigned short* catb  = (unsigned short*)(ws + 27262976L);  // bf16 [B][2H][S]
    unsigned short* binb  = (unsigned short*)(ws + 35651584L);  // bf16 [T*B][DIN]
    unsigned* WB = (unsigned*)(ws + 41943040L);         // 1 MB scan W bf16
    unsigned short* Wib = (unsigned short*)(ws + 42205184L);    // 6 MB W_ih bf16
    unsigned short* hbuf = (unsigned short*)(ws + 43778048L);   // 32 KB h dbuf
    unsigned* flags = (unsigned*)(ws + 43786240L);      // 512 B
    // split-pack buffers (dead-window aliases):
    unsigned short* srchi = (unsigned short*)(ws + 27262976L);  // catb region
    unsigned short* srclo = (unsigned short*)(ws + 31457280L);
    unsigned short* refhi = (unsigned short*)(ws + 35651584L);  // binb region
    unsigned short* reflo = (unsigned short*)(ws + 37748736L);
    unsigned short* hshi  = (unsigned short*)(ws + 16777216L);  // as_bf region
    unsigned short* hslo  = (unsigned short*)(ws + 20971520L);  // refT+a_rT region
    unsigned short* wrefhi = (unsigned short*)(ws + 43786368L); // 0.5 MB
    unsigned short* wreflo = (unsigned short*)(ws + 44048512L); // 0.5 MB
    float* cr  = hs;                                    // alias (hs dead after step 4)
    float* xgf = l;                                     // alias (l dead after a_rT)
    float* xgb = ws + 16777216L;                        // alias (dead after step 6)

    hipMemsetAsync(hbuf, 0, 2 * 2 * B_ * HD_ * 2 + 512, stream);

    // 0) one-time weight packs + hi/lo splits of src/ref/Wref
    transpose_w_bf16<<<dim3(4, 32, 2), 256, 0, stream>>>(Whhf, Whhb, WB);
    pack_bf16<<<dim3((G_ * DIN_ / 4 + 255) / 256), 256, 0, stream>>>(
        Wihf, Wib, (long)G_ * DIN_ / 4);
    pack_bf16<<<dim3((G_ * DIN_ / 4 + 255) / 256), 256, 0, stream>>>(
        Wihb, Wib + (long)G_ * DIN_, (long)G_ * DIN_ / 4);
    pack_hilo<<<dim3(8192), 256, 0, stream>>>(src, srchi, srclo, (long)S_ * B_ * H_ / 4);
    pack_hilo<<<dim3(4096), 256, 0, stream>>>(ref, refhi, reflo, (long)R_ * B_ * H_ / 4);
    pack_hilo<<<dim3(256), 256, 0, stream>>>(Wref, wrefhi, wreflo, (long)H_ * H_ / 4);

    // 1) h_s = tanh(src . Wref^T + bref)  (split-bf16 MFMA, fp32-class acc)
    //    A row s of batch b: src[(s*B+b)*H] -> a_bs=H, lda=B*H; C hs[b][s][o]
    gemm_split<<<dim3(H_ / 64, S_ / 64, B_), 256, 0, stream>>>(
        srchi, srclo, H_, (long)B_ * H_,
        wrefhi, wreflo, 0, H_,
        hs, (long)S_ * H_, H_, bref, 1, H_);

    // 2) l[b][s][r] = sum_h hs[b][s][h]*ref[r][b][h]  (split-bf16 MFMA)
    pack_hilo<<<dim3(8192), 256, 0, stream>>>(hs, hshi, hslo, (long)B_ * S_ * H_ / 4);
    gemm_split<<<dim3(R_ / 64, S_ / 64, B_), 256, 0, stream>>>(
        hshi, hslo, (long)S_ * H_, H_,
        refhi, reflo, H_, (long)B_ * H_,
        l, (long)S_ * R_, R_, nullptr, 0, H_);

    // 3) softmaxes: a_s -> bf16; a_r in place (fp32)
    softmax_cols<<<dim3(R_ / 128, B_), 512, 0, stream>>>(l, as_bf);
    softmax_rows<<<(B_ * S_) / 4, 256, 0, stream>>>(l);

    // 3b) bf16 transposes for the MFMA attention GEMMs
    transpose_ref<<<dim3(R_ / 32, H_ / 32, B_), dim3(32, 8), 0, stream>>>(ref, refT);
    transpose_arT<<<dim3(S_ / 32, R_ / 32, B_), dim3(32, 8), 0, stream>>>(l, a_rT);

    // 4) cat_bf rows 0..511 = h_s^T (bf16)
    transpose_hs<<<dim3(S_ / 32, H_ / 32, B_), dim3(32, 8), 0, stream>>>(hs, catb);

    // 5) cat_bf rows 512..1023: c_s[b,h,s] = sum_r refT[b,h,r]*a_s[b,s,r]  (MFMA)
    gemm56<0><<<dim3(S_ / 64, H_ / 64, B_), 256, 0, stream>>>(
        refT, (long)H_ * R_, R_, as_bf, (long)S_ * R_, R_,
        (void*)(catb + (long)H_ * S_), (long)2 * H_ * S_, S_, R_);

    // 6) c_r[b,r,m] = sum_s cat_bf[b,m,s]*a_rT[b,r,s]  (MFMA, transposed C)
    gemm56<1><<<dim3(R_ / 64, 2 * H_ / 64, B_), 256, 0, stream>>>(
        catb, (long)2 * H_ * S_, S_, a_rT, (long)R_ * S_, S_,
        (void*)cr, (long)R_ * 2 * H_, 2 * H_, S_);

    // 7) bilstm_in -> bf16
    build_bin<<<(R_ * B_ * DIN_ / 4 + 255) / 256, 256, 0, stream>>>(cr, ref, binb);

    // 8) xg = bin . W_ih^T + b_ih + b_hh  via MFMA
    gemm_xg_mfma<<<dim3(G_ / 64, R_ * B_ / 64, 2), 256, 0, stream>>>(
        binb, Wib, bihf, bhhf, bihb, bhhb, xgf, xgb);

    // 9) bi-LSTM scan: 4 blocks/dir, W LDS-resident, deferred-out flag sync
    lstm_scan_s<<<dim3(2 * NBD), dim3(256), 0, stream>>>(
        xgf, xgb, (const uint4*)WB, hbuf, flags, out);
}